// Round 1
// baseline (1677.099 us; speedup 1.0000x reference)
//
#include <hip/hip_runtime.h>
#include <math.h>

#define N_NODES 100000
#define N_EDGES 1600000
// IN = HID = 64, OUT = 40

// ---------------------------------------------------------------------------
// Pass A: per-edge scatter into dual aggregation buffer A[d][0..63] (weight 1-u)
// and A[d][64..127] (weight u). One 64-lane wave per edge (grid-stride).
// Optionally accumulates the in-degree count (pass 1 only).
// ---------------------------------------------------------------------------
__global__ void scatter_kernel(const float* __restrict__ x,
                               const int* __restrict__ src,
                               const int* __restrict__ dst,
                               const float* __restrict__ u,
                               float* __restrict__ A,
                               float* __restrict__ cnt /* may be null */) {
    const int lane = threadIdx.x & 63;
    const int wid  = (blockIdx.x * blockDim.x + threadIdx.x) >> 6;
    const int nw   = (gridDim.x * blockDim.x) >> 6;
    for (int e = wid; e < N_EDGES; e += nw) {
        const int   s  = src[e];
        const int   d  = dst[e];
        const float ue = u[e];
        const float v  = x[(size_t)s * 64 + lane];
        atomicAdd(&A[(size_t)d * 128 + lane],      (1.0f - ue) * v);
        atomicAdd(&A[(size_t)d * 128 + 64 + lane], ue * v);
        if (cnt && lane == 0) atomicAdd(&cnt[d], 1.0f);
    }
}

// ---------------------------------------------------------------------------
// Node update layer 1: h = elu( (A0@W1_0 + A1@W1_1)/max(cnt,1) + x@root1 + b1 )
// 256 threads = 4 nodes/block, 64 threads (one wave) per node, thread j = out col.
// ---------------------------------------------------------------------------
__global__ void node1_kernel(const float* __restrict__ A,
                             const float* __restrict__ cnt,
                             const float* __restrict__ x,
                             const float* __restrict__ W1,     // [2][64][64]
                             const float* __restrict__ root1,  // [64][64]
                             const float* __restrict__ b1,     // [64]
                             float* __restrict__ h) {
    __shared__ float sA[4][128];
    __shared__ float sx[4][64];
    const int g = threadIdx.x >> 6;   // node slot in block
    const int j = threadIdx.x & 63;   // output column
    const int node = blockIdx.x * 4 + g;
    if (node < N_NODES) {
        sA[g][j]      = A[(size_t)node * 128 + j];
        sA[g][j + 64] = A[(size_t)node * 128 + 64 + j];
        sx[g][j]      = x[(size_t)node * 64 + j];
    }
    __syncthreads();
    if (node >= N_NODES) return;

    const float inv = 1.0f / fmaxf(cnt[node], 1.0f);
    float acc0 = 0.f, acc1 = 0.f, accr = 0.f;
#pragma unroll 8
    for (int k = 0; k < 64; ++k) {
        acc0 += sA[g][k]      * W1[k * 64 + j];
        acc1 += sA[g][k + 64] * W1[4096 + k * 64 + j];
        accr += sx[g][k]      * root1[k * 64 + j];
    }
    const float val = (acc0 + acc1) * inv + accr + b1[j];
    h[(size_t)node * 64 + j] = (val > 0.f) ? val : (expf(val) - 1.0f);
}

// ---------------------------------------------------------------------------
// Node update layer 2 + log_softmax:
// o = (B0@W2_0 + B1@W2_1)/max(cnt,1) + h@root2 + b2 ; out = o - max - log(sum exp)
// One wave per node; lanes 0..39 hold outputs; shuffle-reduce max & sum.
// ---------------------------------------------------------------------------
__global__ void node2_kernel(const float* __restrict__ B,
                             const float* __restrict__ cnt,
                             const float* __restrict__ h,
                             const float* __restrict__ W2,     // [2][64][40]
                             const float* __restrict__ root2,  // [64][40]
                             const float* __restrict__ b2,     // [40]
                             float* __restrict__ out) {
    __shared__ float sB[4][128];
    __shared__ float sh[4][64];
    const int g = threadIdx.x >> 6;
    const int j = threadIdx.x & 63;
    const int node = blockIdx.x * 4 + g;
    if (node < N_NODES) {
        sB[g][j]      = B[(size_t)node * 128 + j];
        sB[g][j + 64] = B[(size_t)node * 128 + 64 + j];
        sh[g][j]      = h[(size_t)node * 64 + j];
    }
    __syncthreads();
    if (node >= N_NODES) return;

    float myval = 0.0f;
    float red   = -1e30f;  // identity for max; lanes >=40 contribute this
    if (j < 40) {
        const float inv = 1.0f / fmaxf(cnt[node], 1.0f);
        float acc0 = 0.f, acc1 = 0.f, accr = 0.f;
#pragma unroll 8
        for (int k = 0; k < 64; ++k) {
            acc0 += sB[g][k]      * W2[k * 40 + j];
            acc1 += sB[g][k + 64] * W2[2560 + k * 40 + j];
            accr += sh[g][k]      * root2[k * 40 + j];
        }
        myval = (acc0 + acc1) * inv + accr + b2[j];
        red = myval;
    }
    // wave-wide max over 64 lanes
    for (int off = 32; off; off >>= 1) red = fmaxf(red, __shfl_xor(red, off, 64));
    const float m = red;
    float s = (j < 40) ? expf(myval - m) : 0.0f;
    for (int off = 32; off; off >>= 1) s += __shfl_xor(s, off, 64);
    if (j < 40) out[(size_t)node * 40 + j] = myval - m - logf(s);
}

// ---------------------------------------------------------------------------
extern "C" void kernel_launch(void* const* d_in, const int* in_sizes, int n_in,
                              void* d_out, int out_size, void* d_ws, size_t ws_size,
                              hipStream_t stream) {
    const float* x     = (const float*)d_in[0];
    const int*   ei    = (const int*)  d_in[1];   // (2, E): src then dst
    const float* u     = (const float*)d_in[2];   // (E, 1)
    const float* W1    = (const float*)d_in[3];
    const float* root1 = (const float*)d_in[4];
    const float* b1    = (const float*)d_in[5];
    const float* W2    = (const float*)d_in[6];
    const float* root2 = (const float*)d_in[7];
    const float* b2    = (const float*)d_in[8];
    float*       out   = (float*)d_out;

    const int* src = ei;
    const int* dst = ei + N_EDGES;

    // workspace layout (floats): A[N*128] | cnt[N] | h[N*64]  (~77.2 MB)
    float* A   = (float*)d_ws;
    float* cnt = A + (size_t)N_NODES * 128;
    float* h   = cnt + N_NODES;

    // zero A + cnt (contiguous) every call — harness does not re-poison
    hipMemsetAsync(A, 0, sizeof(float) * ((size_t)N_NODES * 128 + N_NODES), stream);

    const int SC_BLOCKS = 8192;  // grid-stride; 8192*4 waves cover 1.6M edges
    scatter_kernel<<<SC_BLOCKS, 256, 0, stream>>>(x, src, dst, u, A, cnt);
    node1_kernel<<<(N_NODES + 3) / 4, 256, 0, stream>>>(A, cnt, x, W1, root1, b1, h);

    hipMemsetAsync(A, 0, sizeof(float) * (size_t)N_NODES * 128, stream);
    scatter_kernel<<<SC_BLOCKS, 256, 0, stream>>>(h, src, dst, u, A, nullptr);
    node2_kernel<<<(N_NODES + 3) / 4, 256, 0, stream>>>(A, cnt, h, W2, root2, b2, out);
}

// Round 2
// 620.600 us; speedup vs baseline: 2.7024x; 2.7024x over previous
//
#include <hip/hip_runtime.h>
#include <math.h>

#define N_NODES 100000
#define N_EDGES 1600000
// IN = HID = 64, OUT = 40

// ---------------------------------------------------------------------------
// 1) degree histogram: deg[d] = in-degree of d   (int atomics, 400 KB table)
// ---------------------------------------------------------------------------
__global__ void deg_kernel(const int* __restrict__ dst, int* __restrict__ deg) {
    const int t = blockIdx.x * blockDim.x + threadIdx.x;
    if (t * 4 < N_EDGES) {
        const int4 d4 = ((const int4*)dst)[t];
        atomicAdd(&deg[d4.x], 1);
        atomicAdd(&deg[d4.y], 1);
        atomicAdd(&deg[d4.z], 1);
        atomicAdd(&deg[d4.w], 1);
    }
}

// ---------------------------------------------------------------------------
// 2) row allocation: rowstart[d] via wave-prefix + one atomic per wave on a
//    global cursor (row placement order nondeterministic -- harmless, sums
//    are per-node regardless).
// ---------------------------------------------------------------------------
__global__ void alloc_kernel(const int* __restrict__ deg,
                             int* __restrict__ rowstart,
                             int* __restrict__ curpos,
                             int* __restrict__ cursor) {
    const int d    = blockIdx.x * blockDim.x + threadIdx.x;
    const int lane = threadIdx.x & 63;
    const int dg   = (d < N_NODES) ? deg[d] : 0;
    // inclusive wave scan
    int inc = dg;
    for (int off = 1; off < 64; off <<= 1) {
        int tv = __shfl_up(inc, off, 64);
        if (lane >= off) inc += tv;
    }
    const int wavesum = __shfl(inc, 63, 64);
    int base = 0;
    if (lane == 63) base = atomicAdd(cursor, wavesum);
    base = __shfl(base, 63, 64);
    if (d < N_NODES) {
        const int start = base + inc - dg;
        rowstart[d] = start;
        curpos[d]   = start;
    }
}

// ---------------------------------------------------------------------------
// 3) bucket fill: rec[p] = (u_bits << 32) | src, grouped by dst.
// ---------------------------------------------------------------------------
__global__ void bucket_kernel(const int* __restrict__ src,
                              const int* __restrict__ dst,
                              const float* __restrict__ u,
                              int* __restrict__ curpos,
                              unsigned long long* __restrict__ rec) {
    const int t = blockIdx.x * blockDim.x + threadIdx.x;
    if (t * 4 < N_EDGES) {
        const int4   s4 = ((const int4*)src)[t];
        const int4   d4 = ((const int4*)dst)[t];
        const float4 u4 = ((const float4*)u)[t];
        int p;
        p = atomicAdd(&curpos[d4.x], 1);
        rec[p] = ((unsigned long long)__float_as_uint(u4.x) << 32) | (unsigned)s4.x;
        p = atomicAdd(&curpos[d4.y], 1);
        rec[p] = ((unsigned long long)__float_as_uint(u4.y) << 32) | (unsigned)s4.y;
        p = atomicAdd(&curpos[d4.z], 1);
        rec[p] = ((unsigned long long)__float_as_uint(u4.z) << 32) | (unsigned)s4.z;
        p = atomicAdd(&curpos[d4.w], 1);
        rec[p] = ((unsigned long long)__float_as_uint(u4.w) << 32) | (unsigned)s4.w;
    }
}

// ---------------------------------------------------------------------------
// 4) fused layer 1: gather-aggregate + (A0@W0 + A1@W1)/deg + x@root + b, ELU.
//    One 64-lane wave per node; lane = feature. Edge records chunk-loaded
//    64 at a time and broadcast via shuffles.
// ---------------------------------------------------------------------------
__global__ __launch_bounds__(256) void layer1_kernel(
        const int* __restrict__ rowstart, const int* __restrict__ deg,
        const unsigned long long* __restrict__ rec,
        const float* __restrict__ x,
        const float* __restrict__ W1,     // [2][64][64]
        const float* __restrict__ root1,  // [64][64]
        const float* __restrict__ b1,     // [64]
        float* __restrict__ h) {
    __shared__ float sA[4][128];
    __shared__ float sx[4][64];
    const int g = threadIdx.x >> 6;
    const int lane = threadIdx.x & 63;
    const int node = blockIdx.x * 4 + g;
    if (node < N_NODES) {
        const int st = rowstart[node];
        const int dg = deg[node];
        float sum = 0.f, sumu = 0.f;
        int i = st;
        const int end = st + dg;
        while (i < end) {
            int m = end - i; if (m > 64) m = 64;
            unsigned long long r = (lane < m) ? rec[i + lane] : 0ULL;
            int   sidx = (int)(unsigned)(r & 0xffffffffULL);
            float uu   = __uint_as_float((unsigned)(r >> 32));
            if (m == 64) {
                #pragma unroll 8
                for (int t = 0; t < 64; ++t) {
                    const int   s2 = __shfl(sidx, t, 64);
                    const float u2 = __shfl(uu,   t, 64);
                    const float v  = x[(size_t)s2 * 64 + lane];
                    sum  += v;
                    sumu += u2 * v;
                }
            } else {
                #pragma unroll 4
                for (int t = 0; t < m; ++t) {
                    const int   s2 = __shfl(sidx, t, 64);
                    const float u2 = __shfl(uu,   t, 64);
                    const float v  = x[(size_t)s2 * 64 + lane];
                    sum  += v;
                    sumu += u2 * v;
                }
            }
            i += m;
        }
        const float inv = 1.0f / fmaxf((float)dg, 1.0f);
        sA[g][lane]      = (sum - sumu) * inv;  // (1-u) part
        sA[g][lane + 64] = sumu * inv;          // u part
        sx[g][lane]      = x[(size_t)node * 64 + lane];
    }
    __syncthreads();
    if (node >= N_NODES) return;

    float accW = 0.f, accU = 0.f, accR = 0.f;
    #pragma unroll 8
    for (int k = 0; k < 64; ++k) {
        accW += sA[g][k]      * W1[k * 64 + lane];
        accU += sA[g][k + 64] * W1[4096 + k * 64 + lane];
        accR += sx[g][k]      * root1[k * 64 + lane];
    }
    const float val = accW + accU + accR + b1[lane];
    h[(size_t)node * 64 + lane] = (val > 0.f) ? val : (expf(val) - 1.0f);
}

// ---------------------------------------------------------------------------
// 5) fused layer 2 + log_softmax. Same structure, OUT=40.
// ---------------------------------------------------------------------------
__global__ __launch_bounds__(256) void layer2_kernel(
        const int* __restrict__ rowstart, const int* __restrict__ deg,
        const unsigned long long* __restrict__ rec,
        const float* __restrict__ h,
        const float* __restrict__ W2,     // [2][64][40]
        const float* __restrict__ root2,  // [64][40]
        const float* __restrict__ b2,     // [40]
        float* __restrict__ out) {
    __shared__ float sB[4][128];
    __shared__ float sh[4][64];
    const int g = threadIdx.x >> 6;
    const int lane = threadIdx.x & 63;
    const int node = blockIdx.x * 4 + g;
    if (node < N_NODES) {
        const int st = rowstart[node];
        const int dg = deg[node];
        float sum = 0.f, sumu = 0.f;
        int i = st;
        const int end = st + dg;
        while (i < end) {
            int m = end - i; if (m > 64) m = 64;
            unsigned long long r = (lane < m) ? rec[i + lane] : 0ULL;
            int   sidx = (int)(unsigned)(r & 0xffffffffULL);
            float uu   = __uint_as_float((unsigned)(r >> 32));
            if (m == 64) {
                #pragma unroll 8
                for (int t = 0; t < 64; ++t) {
                    const int   s2 = __shfl(sidx, t, 64);
                    const float u2 = __shfl(uu,   t, 64);
                    const float v  = h[(size_t)s2 * 64 + lane];
                    sum  += v;
                    sumu += u2 * v;
                }
            } else {
                #pragma unroll 4
                for (int t = 0; t < m; ++t) {
                    const int   s2 = __shfl(sidx, t, 64);
                    const float u2 = __shfl(uu,   t, 64);
                    const float v  = h[(size_t)s2 * 64 + lane];
                    sum  += v;
                    sumu += u2 * v;
                }
            }
            i += m;
        }
        const float inv = 1.0f / fmaxf((float)dg, 1.0f);
        sB[g][lane]      = (sum - sumu) * inv;
        sB[g][lane + 64] = sumu * inv;
        sh[g][lane]      = h[(size_t)node * 64 + lane];
    }
    __syncthreads();
    if (node >= N_NODES) return;

    float myval = 0.0f;
    float red   = -1e30f;
    if (lane < 40) {
        float accW = 0.f, accU = 0.f, accR = 0.f;
        #pragma unroll 8
        for (int k = 0; k < 64; ++k) {
            accW += sB[g][k]      * W2[k * 40 + lane];
            accU += sB[g][k + 64] * W2[2560 + k * 40 + lane];
            accR += sh[g][k]      * root2[k * 40 + lane];
        }
        myval = accW + accU + accR + b2[lane];
        red = myval;
    }
    for (int off = 32; off; off >>= 1) red = fmaxf(red, __shfl_xor(red, off, 64));
    const float m = red;
    float s = (lane < 40) ? expf(myval - m) : 0.0f;
    for (int off = 32; off; off >>= 1) s += __shfl_xor(s, off, 64);
    if (lane < 40) out[(size_t)node * 40 + lane] = myval - m - logf(s);
}

// ---------------------------------------------------------------------------
extern "C" void kernel_launch(void* const* d_in, const int* in_sizes, int n_in,
                              void* d_out, int out_size, void* d_ws, size_t ws_size,
                              hipStream_t stream) {
    const float* x     = (const float*)d_in[0];
    const int*   ei    = (const int*)  d_in[1];   // (2, E): src row then dst row
    const float* u     = (const float*)d_in[2];   // (E, 1)
    const float* W1    = (const float*)d_in[3];
    const float* root1 = (const float*)d_in[4];
    const float* b1    = (const float*)d_in[5];
    const float* W2    = (const float*)d_in[6];
    const float* root2 = (const float*)d_in[7];
    const float* b2    = (const float*)d_in[8];
    float*       out   = (float*)d_out;

    const int* src = ei;
    const int* dst = ei + N_EDGES;

    // ws layout: deg[N] curpos[N] cursor[1] pad[1] rowstart[N] pad[N%2?..]
    //            rec[E ulong] h[N*64 float]   (~40 MB total)
    int* deg      = (int*)d_ws;
    int* curpos   = deg + N_NODES;
    int* cursor   = curpos + N_NODES;
    int* rowstart = cursor + 2;                      // keep 8B alignment downstream
    unsigned long long* rec = (unsigned long long*)(rowstart + N_NODES + 2);
    float* h      = (float*)(rec + N_EDGES);

    // zero deg + curpos + cursor (contiguous prefix)
    hipMemsetAsync(deg, 0, sizeof(int) * (2 * N_NODES + 2), stream);

    const int EB = (N_EDGES / 4 + 255) / 256;        // 1563 blocks, 4 edges/thread
    deg_kernel<<<EB, 256, 0, stream>>>(dst, deg);
    alloc_kernel<<<(N_NODES + 255) / 256, 256, 0, stream>>>(deg, rowstart, curpos, cursor);
    bucket_kernel<<<EB, 256, 0, stream>>>(src, dst, u, curpos, rec);

    const int NB = (N_NODES + 3) / 4;                // 4 nodes (waves) per block
    layer1_kernel<<<NB, 256, 0, stream>>>(rowstart, deg, rec, x, W1, root1, b1, h);
    layer2_kernel<<<NB, 256, 0, stream>>>(rowstart, deg, rec, h, W2, root2, b2, out);
}

// Round 3
// 522.909 us; speedup vs baseline: 3.2072x; 1.1868x over previous
//
#include <hip/hip_runtime.h>
#include <math.h>

#define NN 100000
#define NE 1600000
// IN = HID = 64, OUT = 40

typedef unsigned long long ull;

// ---------------------------------------------------------------------------
// 1) degree histogram
// ---------------------------------------------------------------------------
__global__ void deg_kernel(const int* __restrict__ dst, int* __restrict__ deg) {
    const int t = blockIdx.x * blockDim.x + threadIdx.x;
    if (t * 4 < NE) {
        const int4 d4 = ((const int4*)dst)[t];
        atomicAdd(&deg[d4.x], 1);
        atomicAdd(&deg[d4.y], 1);
        atomicAdd(&deg[d4.z], 1);
        atomicAdd(&deg[d4.w], 1);
    }
}

// ---------------------------------------------------------------------------
// 2) row allocation via wave-scan + global cursor
// ---------------------------------------------------------------------------
__global__ void alloc_kernel(const int* __restrict__ deg,
                             int* __restrict__ rowstart,
                             int* __restrict__ curpos,
                             int* __restrict__ cursor) {
    const int d    = blockIdx.x * blockDim.x + threadIdx.x;
    const int lane = threadIdx.x & 63;
    const int dg   = (d < NN) ? deg[d] : 0;
    int inc = dg;
    for (int off = 1; off < 64; off <<= 1) {
        int tv = __shfl_up(inc, off, 64);
        if (lane >= off) inc += tv;
    }
    const int wavesum = __shfl(inc, 63, 64);
    int base = 0;
    if (lane == 63) base = atomicAdd(cursor, wavesum);
    base = __shfl(base, 63, 64);
    if (d < NN) {
        const int start = base + inc - dg;
        rowstart[d] = start;
        curpos[d]   = start;
    }
}

// ---------------------------------------------------------------------------
// 3) bucket fill: rec[p] = (u_bits << 32) | src, grouped by dst
// ---------------------------------------------------------------------------
__global__ void bucket_kernel(const int* __restrict__ src,
                              const int* __restrict__ dst,
                              const float* __restrict__ u,
                              int* __restrict__ curpos,
                              ull* __restrict__ rec) {
    const int t = blockIdx.x * blockDim.x + threadIdx.x;
    if (t * 4 < NE) {
        const int4   s4 = ((const int4*)src)[t];
        const int4   d4 = ((const int4*)dst)[t];
        const float4 u4 = ((const float4*)u)[t];
        int p;
        p = atomicAdd(&curpos[d4.x], 1);
        rec[p] = ((ull)__float_as_uint(u4.x) << 32) | (unsigned)s4.x;
        p = atomicAdd(&curpos[d4.y], 1);
        rec[p] = ((ull)__float_as_uint(u4.y) << 32) | (unsigned)s4.y;
        p = atomicAdd(&curpos[d4.z], 1);
        rec[p] = ((ull)__float_as_uint(u4.z) << 32) | (unsigned)s4.z;
        p = atomicAdd(&curpos[d4.w], 1);
        rec[p] = ((ull)__float_as_uint(u4.w) << 32) | (unsigned)s4.w;
    }
}

__device__ __forceinline__ float elu1(float v) {
    return v > 0.f ? v : __expf(v) - 1.f;
}

// ---------------------------------------------------------------------------
// Fused layer 1: block = 256 threads = 4 waves, 64-node tile.
// Phase 1: each wave aggregates 16 nodes (float4 gather, 4 edges in flight)
//          into LDS tile sA[64][132] = [A0*inv | A1*inv].
// Phase 2: GEMM [64 x 128]@W1cat + x@root1; wave w -> cols 16w..16w+15,
//          lane = node; W streamed as wave-uniform scalar loads.
// ---------------------------------------------------------------------------
__global__ __launch_bounds__(256) void flayer1_kernel(
        const int* __restrict__ rowstart, const int* __restrict__ deg,
        const ull* __restrict__ rec, const float* __restrict__ x,
        const float* __restrict__ W1, const float* __restrict__ root1,
        const float* __restrict__ b1, float* __restrict__ h) {
    __shared__ float sA[64][132];
    const int tid  = threadIdx.x;
    const int w    = tid >> 6;
    const int lane = tid & 63;
    const int g    = lane >> 4;
    const int f    = lane & 15;
    const int base = blockIdx.x * 64;

    for (int nn = 0; nn < 16; ++nn) {
        const int nl   = w * 16 + nn;
        const int node = base + nl;
        float4 sum = make_float4(0.f, 0.f, 0.f, 0.f);
        float4 smu = make_float4(0.f, 0.f, 0.f, 0.f);
        int dg = 0;
        if (node < NN) {
            dg = deg[node];
            const int st = rowstart[node];
            for (int c0 = 0; c0 < dg; c0 += 64) {
                int m = dg - c0; if (m > 64) m = 64;
                ull r = 0ULL;
                if (lane < m) r = rec[st + c0 + lane];
                const int   sidx = (int)(unsigned)(r & 0xffffffffULL);
                const float uval = __uint_as_float((unsigned)(r >> 32));
                #pragma unroll 4
                for (int t = 0; t < m; t += 4) {
                    const int sl = t + g;
                    const int   s2 = __shfl(sidx, sl, 64);
                    const float u2 = __shfl(uval, sl, 64);
                    const float4 v = ((const float4*)x)[(size_t)s2 * 16 + f];
                    if (sl < m) {
                        sum.x += v.x; sum.y += v.y; sum.z += v.z; sum.w += v.w;
                        smu.x = fmaf(u2, v.x, smu.x);
                        smu.y = fmaf(u2, v.y, smu.y);
                        smu.z = fmaf(u2, v.z, smu.z);
                        smu.w = fmaf(u2, v.w, smu.w);
                    }
                }
            }
        }
        #pragma unroll
        for (int off = 16; off < 64; off <<= 1) {
            sum.x += __shfl_xor(sum.x, off, 64);
            sum.y += __shfl_xor(sum.y, off, 64);
            sum.z += __shfl_xor(sum.z, off, 64);
            sum.w += __shfl_xor(sum.w, off, 64);
            smu.x += __shfl_xor(smu.x, off, 64);
            smu.y += __shfl_xor(smu.y, off, 64);
            smu.z += __shfl_xor(smu.z, off, 64);
            smu.w += __shfl_xor(smu.w, off, 64);
        }
        if (node < NN) {
            const float inv = 1.0f / fmaxf((float)dg, 1.0f);
            if (g == 0) {
                *(float4*)&sA[nl][4 * f] = make_float4(
                    (sum.x - smu.x) * inv, (sum.y - smu.y) * inv,
                    (sum.z - smu.z) * inv, (sum.w - smu.w) * inv);
            } else if (g == 1) {
                *(float4*)&sA[nl][64 + 4 * f] = make_float4(
                    smu.x * inv, smu.y * inv, smu.z * inv, smu.w * inv);
            }
        }
    }
    __syncthreads();

    // ---- phase 2: per-wave 16-column GEMM slice, lane = node ----
    const int cb    = __builtin_amdgcn_readfirstlane(w * 16);
    const int nl    = lane;
    const int node  = base + nl;
    const int nodec = (node < NN) ? node : (NN - 1);
    float acc[16];
    #pragma unroll
    for (int c = 0; c < 16; ++c) acc[c] = 0.f;

    const float* __restrict__ Wc = W1 + cb;   // [2][64][64] => k*64 contiguous, k=0..127
    #pragma unroll 2
    for (int k4 = 0; k4 < 32; ++k4) {
        const float4 a4 = *(const float4*)&sA[nl][k4 * 4];
        const float av[4] = {a4.x, a4.y, a4.z, a4.w};
        #pragma unroll
        for (int kk = 0; kk < 4; ++kk) {
            const float* wr = Wc + (k4 * 4 + kk) * 64;
            #pragma unroll
            for (int c = 0; c < 16; ++c) acc[c] = fmaf(av[kk], wr[c], acc[c]);
        }
    }
    const float4* __restrict__ xr = (const float4*)(x + (size_t)nodec * 64);
    const float* __restrict__ Rc = root1 + cb;
    #pragma unroll 2
    for (int k4 = 0; k4 < 16; ++k4) {
        const float4 a4 = xr[k4];
        const float av[4] = {a4.x, a4.y, a4.z, a4.w};
        #pragma unroll
        for (int kk = 0; kk < 4; ++kk) {
            const float* wr = Rc + (k4 * 4 + kk) * 64;
            #pragma unroll
            for (int c = 0; c < 16; ++c) acc[c] = fmaf(av[kk], wr[c], acc[c]);
        }
    }
    if (node < NN) {
        float* hr = h + (size_t)node * 64 + cb;
        #pragma unroll
        for (int c4 = 0; c4 < 4; ++c4) {
            float4 o;
            o.x = elu1(acc[c4 * 4 + 0] + b1[cb + c4 * 4 + 0]);
            o.y = elu1(acc[c4 * 4 + 1] + b1[cb + c4 * 4 + 1]);
            o.z = elu1(acc[c4 * 4 + 2] + b1[cb + c4 * 4 + 2]);
            o.w = elu1(acc[c4 * 4 + 3] + b1[cb + c4 * 4 + 3]);
            ((float4*)hr)[c4] = o;
        }
    }
}

// ---------------------------------------------------------------------------
// Fused layer 2 + log_softmax: same structure, OUT=40 (10 cols/wave),
// softmax via LDS bounce.
// ---------------------------------------------------------------------------
__global__ __launch_bounds__(256) void flayer2_kernel(
        const int* __restrict__ rowstart, const int* __restrict__ deg,
        const ull* __restrict__ rec, const float* __restrict__ hbuf,
        const float* __restrict__ W2, const float* __restrict__ root2,
        const float* __restrict__ b2, float* __restrict__ out) {
    __shared__ float sA[64][132];
    __shared__ float sOut[64][44];
    const int tid  = threadIdx.x;
    const int w    = tid >> 6;
    const int lane = tid & 63;
    const int g    = lane >> 4;
    const int f    = lane & 15;
    const int base = blockIdx.x * 64;

    for (int nn = 0; nn < 16; ++nn) {
        const int nl   = w * 16 + nn;
        const int node = base + nl;
        float4 sum = make_float4(0.f, 0.f, 0.f, 0.f);
        float4 smu = make_float4(0.f, 0.f, 0.f, 0.f);
        int dg = 0;
        if (node < NN) {
            dg = deg[node];
            const int st = rowstart[node];
            for (int c0 = 0; c0 < dg; c0 += 64) {
                int m = dg - c0; if (m > 64) m = 64;
                ull r = 0ULL;
                if (lane < m) r = rec[st + c0 + lane];
                const int   sidx = (int)(unsigned)(r & 0xffffffffULL);
                const float uval = __uint_as_float((unsigned)(r >> 32));
                #pragma unroll 4
                for (int t = 0; t < m; t += 4) {
                    const int sl = t + g;
                    const int   s2 = __shfl(sidx, sl, 64);
                    const float u2 = __shfl(uval, sl, 64);
                    const float4 v = ((const float4*)hbuf)[(size_t)s2 * 16 + f];
                    if (sl < m) {
                        sum.x += v.x; sum.y += v.y; sum.z += v.z; sum.w += v.w;
                        smu.x = fmaf(u2, v.x, smu.x);
                        smu.y = fmaf(u2, v.y, smu.y);
                        smu.z = fmaf(u2, v.z, smu.z);
                        smu.w = fmaf(u2, v.w, smu.w);
                    }
                }
            }
        }
        #pragma unroll
        for (int off = 16; off < 64; off <<= 1) {
            sum.x += __shfl_xor(sum.x, off, 64);
            sum.y += __shfl_xor(sum.y, off, 64);
            sum.z += __shfl_xor(sum.z, off, 64);
            sum.w += __shfl_xor(sum.w, off, 64);
            smu.x += __shfl_xor(smu.x, off, 64);
            smu.y += __shfl_xor(smu.y, off, 64);
            smu.z += __shfl_xor(smu.z, off, 64);
            smu.w += __shfl_xor(smu.w, off, 64);
        }
        if (node < NN) {
            const float inv = 1.0f / fmaxf((float)dg, 1.0f);
            if (g == 0) {
                *(float4*)&sA[nl][4 * f] = make_float4(
                    (sum.x - smu.x) * inv, (sum.y - smu.y) * inv,
                    (sum.z - smu.z) * inv, (sum.w - smu.w) * inv);
            } else if (g == 1) {
                *(float4*)&sA[nl][64 + 4 * f] = make_float4(
                    smu.x * inv, smu.y * inv, smu.z * inv, smu.w * inv);
            }
        }
    }
    __syncthreads();

    // ---- phase 2: 10 cols per wave, lane = node ----
    const int cb    = __builtin_amdgcn_readfirstlane(w * 10);
    const int nl    = lane;
    const int node  = base + nl;
    const int nodec = (node < NN) ? node : (NN - 1);
    float acc[10];
    #pragma unroll
    for (int c = 0; c < 10; ++c) acc[c] = 0.f;

    const float* __restrict__ Wc = W2 + cb;   // [2][64][40] => k*40, k=0..127
    #pragma unroll 2
    for (int k4 = 0; k4 < 32; ++k4) {
        const float4 a4 = *(const float4*)&sA[nl][k4 * 4];
        const float av[4] = {a4.x, a4.y, a4.z, a4.w};
        #pragma unroll
        for (int kk = 0; kk < 4; ++kk) {
            const float* wr = Wc + (k4 * 4 + kk) * 40;
            #pragma unroll
            for (int c = 0; c < 10; ++c) acc[c] = fmaf(av[kk], wr[c], acc[c]);
        }
    }
    const float4* __restrict__ hr4 = (const float4*)(hbuf + (size_t)nodec * 64);
    const float* __restrict__ Rc = root2 + cb;
    #pragma unroll 2
    for (int k4 = 0; k4 < 16; ++k4) {
        const float4 a4 = hr4[k4];
        const float av[4] = {a4.x, a4.y, a4.z, a4.w};
        #pragma unroll
        for (int kk = 0; kk < 4; ++kk) {
            const float* wr = Rc + (k4 * 4 + kk) * 40;
            #pragma unroll
            for (int c = 0; c < 10; ++c) acc[c] = fmaf(av[kk], wr[c], acc[c]);
        }
    }
    #pragma unroll
    for (int c = 0; c < 10; ++c) sOut[nl][cb + c] = acc[c] + b2[cb + c];
    __syncthreads();

    // ---- phase 3: per-node log_softmax (threads 0..63) ----
    if (tid < 64) {
        const int node2 = base + tid;
        if (node2 < NN) {
            float mx = -3.0e38f;
            #pragma unroll
            for (int c = 0; c < 40; ++c) mx = fmaxf(mx, sOut[tid][c]);
            float s = 0.f;
            #pragma unroll
            for (int c = 0; c < 40; ++c) s += __expf(sOut[tid][c] - mx);
            const float lse = mx + __logf(s);
            float* orow = out + (size_t)node2 * 40;
            #pragma unroll
            for (int c4 = 0; c4 < 10; ++c4) {
                float4 o;
                o.x = sOut[tid][c4 * 4 + 0] - lse;
                o.y = sOut[tid][c4 * 4 + 1] - lse;
                o.z = sOut[tid][c4 * 4 + 2] - lse;
                o.w = sOut[tid][c4 * 4 + 3] - lse;
                ((float4*)orow)[c4] = o;
            }
        }
    }
}

// ---------------------------------------------------------------------------
extern "C" void kernel_launch(void* const* d_in, const int* in_sizes, int n_in,
                              void* d_out, int out_size, void* d_ws, size_t ws_size,
                              hipStream_t stream) {
    const float* x     = (const float*)d_in[0];
    const int*   ei    = (const int*)  d_in[1];
    const float* u     = (const float*)d_in[2];
    const float* W1    = (const float*)d_in[3];
    const float* root1 = (const float*)d_in[4];
    const float* b1    = (const float*)d_in[5];
    const float* W2    = (const float*)d_in[6];
    const float* root2 = (const float*)d_in[7];
    const float* b2    = (const float*)d_in[8];
    float*       out   = (float*)d_out;

    const int* src = ei;
    const int* dst = ei + NE;

    // ws layout (16B-aligned sections): deg | curpos | cursor(+pad) | rowstart
    //                                   | rec (u64 E) | h (N*64 f32)  ~= 39.6 MB
    char* p = (char*)d_ws;
    int* deg      = (int*)p;  p += (size_t)4 * NN;       // 400000
    int* curpos   = (int*)p;  p += (size_t)4 * NN;       // 800000
    int* cursor   = (int*)p;  p += 16;                   // 800016
    int* rowstart = (int*)p;  p += (size_t)4 * NN;       // 1200016
    ull* rec      = (ull*)p;  p += (size_t)8 * NE;       // 14000016
    float* h      = (float*)p;

    // zero deg + curpos + cursor
    hipMemsetAsync(deg, 0, (size_t)(2 * 4 * NN + 16), stream);

    const int EB = (NE / 4 + 255) / 256;
    deg_kernel<<<EB, 256, 0, stream>>>(dst, deg);
    alloc_kernel<<<(NN + 255) / 256, 256, 0, stream>>>(deg, rowstart, curpos, cursor);
    bucket_kernel<<<EB, 256, 0, stream>>>(src, dst, u, curpos, rec);

    const int NB = (NN + 63) / 64;
    flayer1_kernel<<<NB, 256, 0, stream>>>(rowstart, deg, rec, x, W1, root1, b1, h);
    flayer2_kernel<<<NB, 256, 0, stream>>>(rowstart, deg, rec, h, W2, root2, b2, out);
}